// Round 14
// baseline (283.047 us; speedup 1.0000x reference)
//
#include <hip/hip_runtime.h>
#include <hip/hip_bf16.h>

typedef __attribute__((ext_vector_type(8))) short short8;   // 8 bf16 (4 VGPRs)
typedef __attribute__((ext_vector_type(4))) float f32x4;    // MFMA 16x16 C/D
typedef __attribute__((ext_vector_type(16))) float f32x16;  // MFMA 32x32 C/D

#define NB 8
#define NC 256
#define NN 4096
#define ND 32
#define NCH 16   // j-chunks of 256
#define LOG2E 1.44269504088896340736f

// P tile [2][128][256] ushort, 16B-slot XOR swizzle (validated R8/R10).
#define PIDX(row, col) (((row) << 8) + ((col) ^ (((row) & 15) << 3)))

static __device__ __forceinline__ ushort f2bf(float f) {
  __hip_bfloat16 h = __float2bfloat16(f);
  return reinterpret_cast<ushort&>(h);
}

// ---------------------------------------------------------------------------
// Projection (unchanged): fp32 MAC, bf16 out; Q pre-scaled by log2(e).
//   blockIdx.y==0 : o in [0,64)  -> QK[b][n][64]  (q 0..31, k 32..63)
//   blockIdx.y>=1 : o in [64,320)-> Vt[b][o-64][n]  (V transposed, bf16)
// ---------------------------------------------------------------------------
__global__ __launch_bounds__(256, 4)
void proj_kernel(const float* __restrict__ x,
                 const float* __restrict__ wq, const float* __restrict__ bq,
                 const float* __restrict__ wk, const float* __restrict__ bk,
                 const float* __restrict__ wv, const float* __restrict__ bv,
                 ushort* __restrict__ qk, ushort* __restrict__ vt) {
  __shared__ float Xs[16][128];
  __shared__ float Ws[16][64];
  const int n0 = blockIdx.x * 128;
  const int o0 = blockIdx.y * 64;
  const int b  = blockIdx.z;
  const int t  = threadIdx.x;
  const int og4 = t & 15;
  const int ng  = t >> 4;

  float acc[4][8];
#pragma unroll
  for (int i = 0; i < 4; ++i)
#pragma unroll
    for (int j = 0; j < 8; ++j) acc[i][j] = 0.f;

  const int xs_r = t >> 4;
  const int xs_c = (t & 15) * 4;
  const int ws_o = t & 63;
  const int ws_c = (t >> 6) * 4;
  const float* wrow;
  {
    const int o = o0 + ws_o;
    if (o < 32)      wrow = wq + (size_t)o * NC;
    else if (o < 64) wrow = wk + (size_t)(o - 32) * NC;
    else             wrow = wv + (size_t)(o - 64) * NC;
  }

  for (int c0 = 0; c0 < NC; c0 += 16) {
    __syncthreads();
    const float* xsrc = x + ((size_t)(b * NC + c0 + xs_r)) * NN + n0;
    *(float4*)&Xs[xs_r][xs_c]      = *(const float4*)(xsrc + xs_c);
    *(float4*)&Xs[xs_r][64 + xs_c] = *(const float4*)(xsrc + 64 + xs_c);
    {
      const float4 wv4 = *(const float4*)(wrow + c0 + ws_c);
      Ws[ws_c + 0][ws_o] = wv4.x;
      Ws[ws_c + 1][ws_o] = wv4.y;
      Ws[ws_c + 2][ws_o] = wv4.z;
      Ws[ws_c + 3][ws_o] = wv4.w;
    }
    __syncthreads();
#pragma unroll
    for (int cc = 0; cc < 16; ++cc) {
      const float4 wv4 = *(const float4*)&Ws[cc][og4 * 4];
      const float4 xa  = *(const float4*)&Xs[cc][ng * 8];
      const float4 xb  = *(const float4*)&Xs[cc][ng * 8 + 4];
      const float wvv[4] = {wv4.x, wv4.y, wv4.z, wv4.w};
      const float xaa[8] = {xa.x, xa.y, xa.z, xa.w, xb.x, xb.y, xb.z, xb.w};
#pragma unroll
      for (int i = 0; i < 4; ++i)
#pragma unroll
        for (int j = 0; j < 8; ++j) acc[i][j] += wvv[i] * xaa[j];
    }
  }

  if (blockIdx.y == 0) {
    float bb[4], sc[4];
#pragma unroll
    for (int i = 0; i < 4; ++i) {
      const int o = og4 * 4 + i;
      bb[i] = (o < 32) ? bq[o] : bk[o - 32];
      sc[i] = (o < 32) ? LOG2E : 1.0f;
    }
#pragma unroll
    for (int j = 0; j < 8; ++j) {
      union { ushort u[4]; uint2 v; } pk;
#pragma unroll
      for (int i = 0; i < 4; ++i) pk.u[i] = f2bf((acc[i][j] + bb[i]) * sc[i]);
      *(uint2*)(qk + ((size_t)(b * NN + n0 + ng * 8 + j)) * 64 + og4 * 4) = pk.v;
    }
  } else {
#pragma unroll
    for (int i = 0; i < 4; ++i) {
      const int c = o0 - 64 + og4 * 4 + i;
      const float bb = bv[c];
      union { ushort u[8]; uint4 v; } pk;
#pragma unroll
      for (int j = 0; j < 8; ++j) pk.u[j] = f2bf(acc[i][j] + bb);
      *(uint4*)(vt + ((size_t)(b * NC + c)) * NN + n0 + ng * 8) = pk.v;
    }
  }
}

// ---------------------------------------------------------------------------
// Flash attention: R10 producer/consumer structure + latency pipelining that
// fits the 252-reg/wave budget (R12's overflow fixed).
// 256 blocks x 512 threads. Block = (b, 128 q-rows). j-chunk 256, 17
// intervals, ONE barrier each. P dbuf [2][128][256] swizzled (128 KB).
//  Waves 0-3 (S): rows w*32..+32. Half-chunk K ping-pong (kfA[8]/kfB[8]):
//    issue half1(c) -> compute half0 (kfA) -> issue half0(c+1) ->
//    compute half1 (kfB). K latency fully covered. swapped mfma16(K,Q),
//    exp2 (Q pre-scaled), packed b64 P-writes.
//  Waves 4-7 (PV): consume P[(iv-1)&1]: 64 ch/wave, 32x32x16 MFMA
//    (OA/OB = 128 AGPR); V 3-buffer rotation, 2 groups (~300 cyc) ahead.
// Register frames: S ~110 arch; PV ~70 arch + 128 AGPR -> ~200.  No spill.
// ---------------------------------------------------------------------------
#define S_JT(KF, COL)                                                         \
  do {                                                                        \
    const f32x4 s0 = __builtin_amdgcn_mfma_f32_16x16x32_bf16(KF, qf0, zero,   \
                                                             0, 0, 0);        \
    const f32x4 s1 = __builtin_amdgcn_mfma_f32_16x16x32_bf16(KF, qf1, zero,   \
                                                             0, 0, 0);        \
    union { ushort u[4]; uint2 v; } pk0, pk1;                                 \
    _Pragma("unroll")                                                         \
    for (int r = 0; r < 4; ++r) {                                             \
      const float e0 = exp2f(s0[r]);                                          \
      const float e1 = exp2f(s1[r]);                                          \
      lp0 += e0; lp1 += e1;                                                   \
      pk0.u[r] = f2bf(e0); pk1.u[r] = f2bf(e1);                               \
    }                                                                         \
    *(uint2*)&Pb[PIDX(prow0, (COL) + g16 * 4)] = pk0.v;                       \
    *(uint2*)&Pb[PIDX(prow1, (COL) + g16 * 4)] = pk1.v;                       \
  } while (0)

#define KLOAD(KF, J0)                                                         \
  do {                                                                        \
    _Pragma("unroll")                                                         \
    for (int jt = 0; jt < 8; ++jt)                                            \
      KF[jt] = *(const short8*)(kbase + (size_t)((J0) + jt * 16 + c16) * 64); \
  } while (0)

#define V_LOADG(VS, J0, G)                                                    \
  do {                                                                        \
    VS[0] = *(const short8*)(vbA + (J0) + (G) * 32);                          \
    VS[1] = *(const short8*)(vbB + (J0) + (G) * 32);                          \
    VS[2] = *(const short8*)(vbA + (J0) + (G) * 32 + 16);                     \
    VS[3] = *(const short8*)(vbB + (J0) + (G) * 32 + 16);                     \
  } while (0)

#define V_COMPG(VS, G)                                                        \
  do {                                                                        \
    _Pragma("unroll")                                                         \
    for (int k = 0; k < 2; ++k) {                                             \
      const int jo = (G) * 32 + k * 16;                                       \
      _Pragma("unroll")                                                       \
      for (int isub = 0; isub < 4; ++isub) {                                  \
        const short8 pa =                                                     \
            *(const short8*)&Pb[PIDX(isub * 32 + c32, jo + l5 * 8)];          \
        OA[isub] = __builtin_amdgcn_mfma_f32_32x32x16_bf16(                   \
            pa, VS[k * 2], OA[isub], 0, 0, 0);                                \
        OB[isub] = __builtin_amdgcn_mfma_f32_32x32x16_bf16(                   \
            pa, VS[k * 2 + 1], OB[isub], 0, 0, 0);                            \
      }                                                                       \
    }                                                                         \
  } while (0)

__global__ __launch_bounds__(512, 1)
void attn_kernel(const ushort* __restrict__ qk, const ushort* __restrict__ vt,
                 const float* __restrict__ x, const float* __restrict__ gamma,
                 float* __restrict__ out) {
  __shared__ __align__(16) ushort P[2][128 * 256];   // 128 KB, swizzled
  __shared__ __align__(16) float lL[128];

  const int lin  = blockIdx.x;
  const int b    = lin & 7;              // XCD swizzle: batch per XCD L2
  const int i0   = (lin >> 3) * 128;
  const int t    = threadIdx.x;
  const int w    = t >> 6;               // 0..7
  const int lane = t & 63;
  const int g16  = lane >> 4;
  const int c16  = lane & 15;
  const int l5   = lane >> 5;
  const int c32  = lane & 31;

  const f32x4 zero = {0.f, 0.f, 0.f, 0.f};
  const bool isS = (w < 4);

  // ---- S state (waves 0-3): 32 q-rows each ----
  const int prow0 = w * 32 + c16;
  const int prow1 = prow0 + 16;
  short8 qf0, qf1;
  short8 kfA[8], kfB[8];
  float lp0 = 0.f, lp1 = 0.f;
  const ushort* kbase = qk + ((size_t)b * NN) * 64 + 32 + g16 * 8;
  if (isS) {
    qf0 = *(const short8*)(qk + ((size_t)(b * NN + i0 + prow0)) * 64 + g16 * 8);
    qf1 = *(const short8*)(qk + ((size_t)(b * NN + i0 + prow1)) * 64 + g16 * 8);
    KLOAD(kfA, 0);   // prologue: half0 of chunk 0
  }

  // ---- PV state (waves 4-7): 64 channels each ----
  const int p = w - 4;
  f32x16 OA[4], OB[4];
  const ushort* vbA = nullptr; const ushort* vbB = nullptr;
  if (!isS) {
#pragma unroll
    for (int isub = 0; isub < 4; ++isub)
#pragma unroll
      for (int e = 0; e < 16; ++e) { OA[isub][e] = 0.f; OB[isub][e] = 0.f; }
    vbA = vt + ((size_t)(b * NC + p * 64 + c32)) * NN + l5 * 8;
    vbB = vt + ((size_t)(b * NC + p * 64 + 32 + c32)) * NN + l5 * 8;
  }

  for (int iv = 0; iv <= NCH; ++iv) {
    if (isS) {
      if (iv < NCH) {
        ushort* Pb = P[iv & 1];
        const int j0 = iv * 256;
        // issue half1(iv); compute half0 (kfA) meanwhile
        KLOAD(kfB, j0 + 128);
        S_JT(kfA[0], 0);   S_JT(kfA[1], 16);  S_JT(kfA[2], 32);
        S_JT(kfA[3], 48);  S_JT(kfA[4], 64);  S_JT(kfA[5], 80);
        S_JT(kfA[6], 96);  S_JT(kfA[7], 112);
        // issue half0(iv+1); compute half1 (kfB)
        if (iv + 1 < NCH) KLOAD(kfA, j0 + 256);
        S_JT(kfB[0], 128); S_JT(kfB[1], 144); S_JT(kfB[2], 160);
        S_JT(kfB[3], 176); S_JT(kfB[4], 192); S_JT(kfB[5], 208);
        S_JT(kfB[6], 224); S_JT(kfB[7], 240);
      } else {
        // interval 16: finalize row sums (reduce over the 4 g16 groups)
        lp0 += __shfl_xor(lp0, 16); lp0 += __shfl_xor(lp0, 32);
        lp1 += __shfl_xor(lp1, 16); lp1 += __shfl_xor(lp1, 32);
        if (g16 == 0) { lL[prow0] = lp0; lL[prow1] = lp1; }
      }
    } else if (iv >= 1) {
      const int ch = iv - 1;
      const ushort* Pb = P[ch & 1];
      const int j0 = ch * 256;
      short8 v0[4], v1[4], v2[4];
      // 2-group-ahead 3-buffer rotation over the 8 groups (2 ji each)
      V_LOADG(v0, j0, 0);
      V_LOADG(v1, j0, 1);
      __builtin_amdgcn_s_setprio(1);
      V_LOADG(v2, j0, 2);  V_COMPG(v0, 0);
      V_LOADG(v0, j0, 3);  V_COMPG(v1, 1);
      V_LOADG(v1, j0, 4);  V_COMPG(v2, 2);
      V_LOADG(v2, j0, 5);  V_COMPG(v0, 3);
      V_LOADG(v0, j0, 6);  V_COMPG(v1, 4);
      V_LOADG(v1, j0, 7);  V_COMPG(v2, 5);
      V_COMPG(v0, 6);      V_COMPG(v1, 7);
      __builtin_amdgcn_s_setprio(0);
    }
    __syncthreads();
  }

  // ---- epilogue: PV waves write out = gamma*O/l + x ----
  if (!isS) {
    const float g = gamma[0];
#pragma unroll
    for (int isub = 0; isub < 4; ++isub) {
#pragma unroll
      for (int q = 0; q < 4; ++q) {
        const int r0 = isub * 32 + q * 8 + l5 * 4;   // D row: (reg&3)+8q+4*l5
        const f32x4 li = *(const f32x4*)&lL[r0];
        f32x4 gi;
#pragma unroll
        for (int r = 0; r < 4; ++r) gi[r] = g / li[r];
        {
          const int c = p * 64 + c32;
          const size_t base = ((size_t)(b * NC + c)) * NN + i0 + r0;
          const f32x4 xv = *(const f32x4*)(x + base);
          f32x4 ov;
#pragma unroll
          for (int r = 0; r < 4; ++r) ov[r] = OA[isub][q * 4 + r] * gi[r] + xv[r];
          *(f32x4*)(out + base) = ov;
        }
        {
          const int c = p * 64 + 32 + c32;
          const size_t base = ((size_t)(b * NC + c)) * NN + i0 + r0;
          const f32x4 xv = *(const f32x4*)(x + base);
          f32x4 ov;
#pragma unroll
          for (int r = 0; r < 4; ++r) ov[r] = OB[isub][q * 4 + r] * gi[r] + xv[r];
          *(f32x4*)(out + base) = ov;
        }
      }
    }
  }
}

extern "C" void kernel_launch(void* const* d_in, const int* in_sizes, int n_in,
                              void* d_out, int out_size, void* d_ws, size_t ws_size,
                              hipStream_t stream) {
  const float* x  = (const float*)d_in[0];
  const float* wq = (const float*)d_in[1];
  const float* bq = (const float*)d_in[2];
  const float* wk = (const float*)d_in[3];
  const float* bk = (const float*)d_in[4];
  const float* wv = (const float*)d_in[5];
  const float* bv = (const float*)d_in[6];
  const float* gm = (const float*)d_in[7];
  float* outp = (float*)d_out;

  ushort* qkw = (ushort*)d_ws;                       // [B][N][64]  bf16, 4 MB
  ushort* vtw = qkw + (size_t)NB * NN * 64;          // [B][C][N]   bf16, 16 MB

  proj_kernel<<<dim3(NN / 128, 5, NB), 256, 0, stream>>>(
      x, wq, bq, wk, bk, wv, bv, qkw, vtw);
  attn_kernel<<<dim3((NN / 128) * NB), 512, 0, stream>>>(qkw, vtw, x, gm, outp);
}